// Round 2
// baseline (1310.901 us; speedup 1.0000x reference)
//
#include <hip/hip_runtime.h>

// Spatially-varying 17x17 blur.
// img:     (B=4, C=3, 272, 272) fp32, pre-padded
// kernels: (16, 1, 289, 65536) fp32, per-pixel taps (normalized)
// idx:     scalar int (device)
// out:     (4, 3, 256, 256) fp32
//
// R2: k-split decisive experiment. R1 (4x occupancy) moved dur_us only
// -23 us -> kernel is NOT latency-bound; dur_us is dominated by the
// ~785 us harness poison-fill + ~500 us restore. Remaining kernel-side
// theories are traffic stories: kern re-fetch x4 (b-replicas) and img
// L2-thrash under the kern stream. This version kills both:
//  - blockIdx.z = kh-chunk (rows {0-4,5-8,9-12,13-16}): disjoint img rows
//    per z -> img read ~once; per-thread stream 4x shorter; 4096 blocks
//    -> ~24 waves/CU resident.
//  - b-replicas (ids x+256b+1024z, fixed x,z) land on the SAME CU
//    ((id/8)%32 is b-invariant) and are co-resident -> kern stays ~76 MB HBM.
//  - partials merged via device-scope atomicAdd (4 adders/address,
//    contention-free); out zeroed by hipMemsetAsync (re-poison safe).
// If dur_us doesn't drop >=25 us, the kernel is at its ~85 MB BW floor and
// the metric is harness-bound -> declare roofline.

#define KS 17
#define HP 256
#define WP 256
#define IW (WP + KS - 1)          // 272
#define IH (HP + KS - 1)          // 272
#define NPIX (HP * WP)            // 65536
#define CH_STRIDE (IW * IH)       // 73984

__global__ __launch_bounds__(256, 4) void blur_pixel_kernel(
    const float* __restrict__ img,
    const float* __restrict__ kernels,
    const int* __restrict__ idx_p,
    float* __restrict__ out)
{
    const int p = blockIdx.x * 256 + threadIdx.x;   // pixel id
    const int b = blockIdx.y;                       // batch 0..3
    const int z = blockIdx.z;                       // kh-chunk 0..3
    const int y = p >> 8;                           // WP == 256
    const int x = p & 255;

    // kh rows for this chunk: z=0 -> [0,5), z=1 -> [5,9), z=2 -> [9,13), z=3 -> [13,17)
    const int kh0 = (z == 0) ? 0 : 1 + 4 * z;
    const int khN = kh0 + ((z == 0) ? 5 : 4);

    // kernels[idx, 0, k, p]
    const float* kern = kernels + (long)idx_p[0] * (long)(KS * KS) * (long)NPIX + p;
    // img[b, 0, y, x]
    const float* imgp = img + (long)b * 3 * CH_STRIDE + y * IW + x;

    float a0 = 0.0f, a1 = 0.0f, a2 = 0.0f;

    for (int kh = kh0; kh < khN; ++kh) {
        const float* krow = kern + (long)(kh * KS) * NPIX;
        const float* irow = imgp + kh * IW;
#pragma unroll
        for (int kw = 0; kw < KS; ++kw) {
            const float w = krow[(long)kw * NPIX];
            a0 = fmaf(w, irow[kw], a0);
            a1 = fmaf(w, irow[CH_STRIDE + kw], a1);
            a2 = fmaf(w, irow[2 * CH_STRIDE + kw], a2);
        }
    }

    float* op = out + (long)b * 3 * NPIX + p;
    atomicAdd(op, a0);
    atomicAdd(op + NPIX, a1);
    atomicAdd(op + 2 * NPIX, a2);
}

extern "C" void kernel_launch(void* const* d_in, const int* in_sizes, int n_in,
                              void* d_out, int out_size, void* d_ws, size_t ws_size,
                              hipStream_t stream) {
    const float* img     = (const float*)d_in[0];
    const float* kernels = (const float*)d_in[1];
    const int*   idx     = (const int*)d_in[2];
    float*       out     = (float*)d_out;

    // out is re-poisoned between iterations; zero it before atomic accumulation.
    hipMemsetAsync(out, 0, out_size, stream);
    blur_pixel_kernel<<<dim3(NPIX / 256, 4, 4), dim3(256), 0, stream>>>(img, kernels, idx, out);
}